// Round 15
// baseline (326.787 us; speedup 1.0000x reference)
//
#include <hip/hip_runtime.h>

#define NN   50000
#define NE   800000
#define HID  128
#define OUTD 40
#define NBLK 196  // ceil(NN/256)
#define LIN_BLKS ((NN + 127) / 128)   // 391
#define DEG_BLKS ((NE + 255) / 256)   // 3125
#define AGG_BLKS 2048

typedef float f32x4  __attribute__((ext_vector_type(4)));
typedef int   i32x4  __attribute__((ext_vector_type(4)));
typedef short bf16x8 __attribute__((ext_vector_type(8)));

// ---------- helpers ----------
__device__ __forceinline__ f32x4 mfma(bf16x8 a, bf16x8 b, f32x4 c) {
  return __builtin_amdgcn_mfma_f32_16x16x32_bf16(a, b, c, 0, 0, 0);
}
__device__ __forceinline__ unsigned short f2bf(float f) {
  unsigned u = __builtin_bit_cast(unsigned, f);
  u += 0x7fffu + ((u >> 16) & 1u);
  return (unsigned short)(u >> 16);
}
__device__ __forceinline__ unsigned pack2(float lo, float hi) {
  return (unsigned)f2bf(lo) | ((unsigned)f2bf(hi) << 16);
}
__device__ __forceinline__ float bflo(unsigned v){ return __builtin_bit_cast(float, v << 16); }
__device__ __forceinline__ float bfhi(unsigned v){ return __builtin_bit_cast(float, v & 0xffff0000u); }
__device__ __forceinline__ float bf2f(unsigned short u){ return __builtin_bit_cast(float, (unsigned)u << 16); }
__device__ __forceinline__ void acc8(float* a, uint4 v) {
  a[0] += bflo(v.x); a[1] += bfhi(v.x);
  a[2] += bflo(v.y); a[3] += bfhi(v.y);
  a[4] += bflo(v.z); a[5] += bfhi(v.z);
  a[6] += bflo(v.w); a[7] += bfhi(v.w);
}

__global__ void k_blocksum(const int* __restrict__ deg, int* __restrict__ bsum) {
  __shared__ int s[256];
  int t = threadIdx.x, i = blockIdx.x * 256 + t;
  s[t] = (i < NN) ? deg[i] : 0;
  __syncthreads();
  for (int o = 128; o > 0; o >>= 1) { if (t < o) s[t] += s[t + o]; __syncthreads(); }
  if (t == 0) bsum[blockIdx.x] = s[0];
}

// fused: per-block exclusive base (reduce bsum[0..blockIdx)) + local scan
__global__ void k_scan3(const int* __restrict__ deg, const int* __restrict__ bsum,
                        int* __restrict__ offs, float* __restrict__ dinv) {
  __shared__ int sb[256];
  __shared__ int s[256];
  int t = threadIdx.x, i = blockIdx.x * 256 + t;
  sb[t] = (t < NBLK && t < blockIdx.x) ? bsum[t] : 0;
  int v = (i < NN) ? deg[i] : 0;
  s[t] = v;
  __syncthreads();
  for (int o = 128; o > 0; o >>= 1) { if (t < o) sb[t] += sb[t + o]; __syncthreads(); }
  for (int o = 1; o < 256; o <<= 1) {
    int x = (t >= o) ? s[t - o] : 0;
    __syncthreads(); s[t] += x; __syncthreads();
  }
  int off = sb[0] + s[t] - v;  // exclusive within-array offset
  if (i < NN) {
    offs[i] = off;
    dinv[i] = 1.0f / (float)(v > 0 ? v : 1);
  }
  if (i == 0) offs[NN] = NE;
}

// no atomics: position precomputed in k_deg_lin
__global__ void k_fill(const int* __restrict__ src, const int* __restrict__ dst,
                       const int* __restrict__ pos, const int* __restrict__ offs,
                       int* __restrict__ csr) {
  int i = blockIdx.x * blockDim.x + threadIdx.x;
  if (i < NE) {
    csr[offs[dst[i]] + pos[i]] = src[i];
  }
}

// ---------- weight prep: transpose + bf16 cast into ws; also zeros deg ----------
// wt layout: m=0 WtIn, m=1..3 WtL[i], m=4..6 WtR[i], m=7 WtC1, then WtC2 [48][128]
__global__ void k_prep(const float* __restrict__ Win, const float* __restrict__ Wl,
                       const float* __restrict__ Wr, const float* __restrict__ Wc1,
                       const float* __restrict__ Wc2, unsigned short* __restrict__ wt,
                       int* __restrict__ deg) {
  int idx = blockIdx.x * 256 + threadIdx.x;
  if (idx < NN) deg[idx] = 0;  // folded memset
  const int NMAIN = 8 * 16384;
  if (idx >= NMAIN + 48 * 128) return;
  float v;
  if (idx < NMAIN) {
    int m = idx >> 14, rem = idx & 16383;
    int n = rem >> 7, k = rem & 127;
    const float* s;
    if (m == 0) s = Win;
    else if (m <= 3) s = Wl + (m - 1) * 16384;
    else if (m <= 6) s = Wr + (m - 4) * 16384;
    else s = Wc1;
    v = s[k * 128 + n];
  } else {
    int rem = idx - NMAIN;
    int n = rem >> 7, k = rem & 127;
    v = (n < OUTD) ? Wc2[k * OUTD + n] : 0.f;
  }
  wt[idx] = f2bf(v);
}

// ---------- lin_in body (r10 k_lin_in, as device function) ----------
__device__ __forceinline__ void lin_in_body(int bid, const float* __restrict__ x,
                                            const unsigned short* __restrict__ Wt,
                                            const float* __restrict__ bias,
                                            unsigned short* __restrict__ hout) {
  const int lane = threadIdx.x & 63, w = threadIdx.x >> 6;
  const int wr = w >> 1, wc = w & 1;
  const int r15 = lane & 15, khi = lane >> 4;
  const int mbase = bid * 128 + wr * 64, nbase = wc * 64;
  f32x4 acc[4][4] = {};
#pragma unroll
  for (int ks = 0; ks < 4; ++ks) {
    const int kk = ks * 32 + khi * 8;
    bf16x8 af[4], bq[4];
#pragma unroll
    for (int i = 0; i < 4; i++) {
      int row = mbase + i * 16 + r15; row = row < NN ? row : NN - 1;
      const f32x4* p = (const f32x4*)(x + row * HID + kk);
      f32x4 lo = p[0], hi = p[1];
      i32x4 t;
      t[0] = pack2(lo[0], lo[1]); t[1] = pack2(lo[2], lo[3]);
      t[2] = pack2(hi[0], hi[1]); t[3] = pack2(hi[2], hi[3]);
      af[i] = __builtin_bit_cast(bf16x8, t);
    }
#pragma unroll
    for (int j = 0; j < 4; j++) {
      int col = nbase + j * 16 + r15;
      bq[j] = *(const bf16x8*)(Wt + col * HID + kk);
    }
#pragma unroll
    for (int i = 0; i < 4; i++)
#pragma unroll
      for (int j = 0; j < 4; j++) acc[i][j] = mfma(af[i], bq[j], acc[i][j]);
  }
  float b4[4];
#pragma unroll
  for (int j = 0; j < 4; j++) b4[j] = bias[nbase + j * 16 + r15];
#pragma unroll
  for (int i = 0; i < 4; i++) {
    const int rb = mbase + i * 16 + khi * 4;
#pragma unroll
    for (int e = 0; e < 4; e++) {
      const int r = rb + e;
      if (r < NN) {
#pragma unroll
        for (int j = 0; j < 4; j++)
          hout[r * HID + nbase + j * 16 + r15] = f2bf(acc[i][j][e] + b4[j]);
      }
    }
  }
}

// ---------- fused: h0 GEMM (blocks 0..390) || deg count+rank (blocks 391..) --
__global__ __launch_bounds__(256) void k_deg_lin(const int* __restrict__ dst,
                                                 int* __restrict__ deg,
                                                 int* __restrict__ pos,
                                                 const float* __restrict__ x,
                                                 const unsigned short* __restrict__ Wt,
                                                 const float* __restrict__ bias,
                                                 unsigned short* __restrict__ hout) {
  if (blockIdx.x < LIN_BLKS) {
    lin_in_body(blockIdx.x, x, Wt, bias, hout);
  } else {
    int i = (blockIdx.x - LIN_BLKS) * 256 + threadIdx.x;
    if (i < NE) pos[i] = atomicAdd(&deg[dst[i]], 1);
  }
}

// ---------- gather body (r10 k_agg, as device function) ----------
__device__ __forceinline__ void agg_body(int abid, const unsigned short* __restrict__ h,
                                         const int* __restrict__ csr,
                                         const int* __restrict__ offs,
                                         const float* __restrict__ dinv,
                                         unsigned short* __restrict__ agg) {
  const int lane = threadIdx.x & 63;
  const int c = lane & 15;   // uint4 index within row (16 x 16B = 256B)
  const int q = lane >> 4;   // quarter 0..3: row within 4-row group
  int gw = (abid * 256 + (int)threadIdx.x) >> 6;
  const int nw = (AGG_BLKS * 256) >> 6;  // 8192
  const uint4* h4 = (const uint4*)h;  // row stride = 16 uint4
  uint4* ag4 = (uint4*)agg;
  for (int n = gw; n < NN; n += nw) {
    const int s = offs[n], e = offs[n + 1];
    float a[8] = {0, 0, 0, 0, 0, 0, 0, 0};
    float b[8] = {0, 0, 0, 0, 0, 0, 0, 0};
    int k = s;
    int ia = 0, ib = 0;
    bool have = (k + 8 <= e);
    if (have) { ia = csr[k + q]; ib = csr[k + 4 + q]; }
    while (have) {
      uint4 va = h4[ia * 16 + c];
      uint4 vb = h4[ib * 16 + c];
      k += 8;
      have = (k + 8 <= e);
      if (have) { ia = csr[k + q]; ib = csr[k + 4 + q]; }  // prefetch next batch
      acc8(a, va);
      acc8(b, vb);
    }
    for (; k < e; k += 4) {  // tail 1-7 rows, predicated per quarter
      if (k + q < e) {
        uint4 v = h4[csr[k + q] * 16 + c];
        acc8(a, v);
      }
    }
    float f0 = a[0] + b[0], f1 = a[1] + b[1], f2 = a[2] + b[2], f3 = a[3] + b[3];
    float f4 = a[4] + b[4], f5 = a[5] + b[5], f6 = a[6] + b[6], f7 = a[7] + b[7];
    f0 += __shfl_xor(f0, 16); f1 += __shfl_xor(f1, 16);
    f2 += __shfl_xor(f2, 16); f3 += __shfl_xor(f3, 16);
    f4 += __shfl_xor(f4, 16); f5 += __shfl_xor(f5, 16);
    f6 += __shfl_xor(f6, 16); f7 += __shfl_xor(f7, 16);
    f0 += __shfl_xor(f0, 32); f1 += __shfl_xor(f1, 32);
    f2 += __shfl_xor(f2, 32); f3 += __shfl_xor(f3, 32);
    f4 += __shfl_xor(f4, 32); f5 += __shfl_xor(f5, 32);
    f6 += __shfl_xor(f6, 32); f7 += __shfl_xor(f7, 32);
    if (q == 0) {
      float di = dinv[n];
      uint4 o;
      o.x = pack2(f0 * di, f1 * di);
      o.y = pack2(f2 * di, f3 * di);
      o.z = pack2(f4 * di, f5 * di);
      o.w = pack2(f6 * di, f7 * di);
      ag4[n * 16 + c] = o;
    }
  }
}

// ---------- fused per layer: part = h@WtL + bl (blocks 0..390, no relu)
//            || gather agg from h (blocks 391..2438) ----------
// Self-GEMM depends only on h, so it hides entirely under the gather.
__global__ __launch_bounds__(256) void k_agg_lin(const unsigned short* __restrict__ h,
                                                 const int* __restrict__ csr,
                                                 const int* __restrict__ offs,
                                                 const float* __restrict__ dinv,
                                                 unsigned short* __restrict__ agg,
                                                 const unsigned short* __restrict__ WtL,
                                                 const float* __restrict__ bias,
                                                 unsigned short* __restrict__ part) {
  if (blockIdx.x >= LIN_BLKS) {
    agg_body(blockIdx.x - LIN_BLKS, h, csr, offs, dinv, agg);
    return;
  }
  const int lane = threadIdx.x & 63, w = threadIdx.x >> 6;
  const int wr = w >> 1, wc = w & 1;
  const int r15 = lane & 15, khi = lane >> 4;
  const int mbase = blockIdx.x * 128 + wr * 64, nbase = wc * 64;
  f32x4 acc[4][4] = {};
#pragma unroll
  for (int ks = 0; ks < 4; ++ks) {
    const int kk = ks * 32 + khi * 8;
    bf16x8 af[4], bq[4];
#pragma unroll
    for (int i = 0; i < 4; i++) {
      int row = mbase + i * 16 + r15; row = row < NN ? row : NN - 1;
      af[i] = *(const bf16x8*)(h + row * HID + kk);
    }
#pragma unroll
    for (int j = 0; j < 4; j++) {
      int col = nbase + j * 16 + r15;
      bq[j] = *(const bf16x8*)(WtL + col * HID + kk);
    }
#pragma unroll
    for (int i = 0; i < 4; i++)
#pragma unroll
      for (int j = 0; j < 4; j++) acc[i][j] = mfma(af[i], bq[j], acc[i][j]);
  }
  float b4[4];
#pragma unroll
  for (int j = 0; j < 4; j++) b4[j] = bias[nbase + j * 16 + r15];
#pragma unroll
  for (int i = 0; i < 4; i++) {
    const int rb = mbase + i * 16 + khi * 4;
#pragma unroll
    for (int e = 0; e < 4; e++) {
      const int r = rb + e;
      if (r < NN) {
#pragma unroll
        for (int j = 0; j < 4; j++)
          part[r * HID + nbase + j * 16 + r15] = f2bf(acc[i][j][e] + b4[j]);
      }
    }
  }
}

// ---------- finish layer: h_next = relu(part + agg @ WtR) ----------
__global__ __launch_bounds__(256) void k_layer2(const unsigned short* __restrict__ part,
                                                const unsigned short* __restrict__ ag,
                                                const unsigned short* __restrict__ WtR,
                                                unsigned short* __restrict__ hout) {
  const int lane = threadIdx.x & 63, w = threadIdx.x >> 6;
  const int wr = w >> 1, wc = w & 1;
  const int r15 = lane & 15, khi = lane >> 4;
  const int mbase = blockIdx.x * 128 + wr * 64, nbase = wc * 64;
  f32x4 acc[4][4] = {};
#pragma unroll
  for (int ks = 0; ks < 4; ++ks) {
    const int kk = ks * 32 + khi * 8;
    bf16x8 af[4], bq[4];
#pragma unroll
    for (int i = 0; i < 4; i++) {
      int row = mbase + i * 16 + r15; row = row < NN ? row : NN - 1;
      af[i] = *(const bf16x8*)(ag + row * HID + kk);
    }
#pragma unroll
    for (int j = 0; j < 4; j++) {
      int col = nbase + j * 16 + r15;
      bq[j] = *(const bf16x8*)(WtR + col * HID + kk);
    }
#pragma unroll
    for (int i = 0; i < 4; i++)
#pragma unroll
      for (int j = 0; j < 4; j++) acc[i][j] = mfma(af[i], bq[j], acc[i][j]);
  }
#pragma unroll
  for (int i = 0; i < 4; i++) {
    const int rb = mbase + i * 16 + khi * 4;
#pragma unroll
    for (int e = 0; e < 4; e++) {
      const int r = rb + e;
      if (r < NN) {
#pragma unroll
        for (int j = 0; j < 4; j++) {
          const int col = nbase + j * 16 + r15;
          float v = acc[i][j][e] + bf2f(part[r * HID + col]);
          v = fmaxf(v, 0.f);
          hout[r * HID + col] = f2bf(v);
        }
      }
    }
  }
}

// ---------- classifier: out = relu((h1+h2+h3)@Wc1+bc1)@Wc2+bc2 ----------
__global__ __launch_bounds__(256) void k_cls(const unsigned short* __restrict__ h1,
                                             const unsigned short* __restrict__ h2,
                                             const unsigned short* __restrict__ h3,
                                             const unsigned short* __restrict__ WtC1,
                                             const float* __restrict__ bc1,
                                             const unsigned short* __restrict__ WtC2,
                                             const float* __restrict__ bc2,
                                             float* __restrict__ out) {
  __shared__ unsigned short hc[128 * 136];  // padded row stride 136
  const int lane = threadIdx.x & 63, w = threadIdx.x >> 6;
  const int wr = w >> 1, wc = w & 1;
  const int r15 = lane & 15, khi = lane >> 4;
  const int mbase = blockIdx.x * 128 + wr * 64, nbase = wc * 64;
  // stage 1: hc = relu((h1+h2+h3) @ Wc1 + bc1)
  {
    f32x4 acc[4][4] = {};
#pragma unroll
    for (int ks = 0; ks < 4; ++ks) {
      const int kk = ks * 32 + khi * 8;
      bf16x8 af[4], bq[4];
#pragma unroll
      for (int i = 0; i < 4; i++) {
        int row = mbase + i * 16 + r15; row = row < NN ? row : NN - 1;
        i32x4 u = *(const i32x4*)(h1 + row * HID + kk);
        i32x4 v = *(const i32x4*)(h2 + row * HID + kk);
        i32x4 q = *(const i32x4*)(h3 + row * HID + kk);
        i32x4 t;
#pragma unroll
        for (int cc = 0; cc < 4; cc++) {
          unsigned uu = u[cc], vv = v[cc], qq = q[cc];
          t[cc] = pack2(bflo(uu) + bflo(vv) + bflo(qq), bfhi(uu) + bfhi(vv) + bfhi(qq));
        }
        af[i] = __builtin_bit_cast(bf16x8, t);
      }
#pragma unroll
      for (int j = 0; j < 4; j++) {
        int col = nbase + j * 16 + r15;
        bq[j] = *(const bf16x8*)(WtC1 + col * HID + kk);
      }
#pragma unroll
      for (int i = 0; i < 4; i++)
#pragma unroll
        for (int j = 0; j < 4; j++) acc[i][j] = mfma(af[i], bq[j], acc[i][j]);
    }
    float b4[4];
#pragma unroll
    for (int j = 0; j < 4; j++) b4[j] = bc1[nbase + j * 16 + r15];
#pragma unroll
    for (int i = 0; i < 4; i++) {
      const int rT = wr * 64 + i * 16 + khi * 4;
#pragma unroll
      for (int e = 0; e < 4; e++) {
#pragma unroll
        for (int j = 0; j < 4; j++) {
          float v = fmaxf(acc[i][j][e] + b4[j], 0.f);
          hc[(rT + e) * 136 + nbase + j * 16 + r15] = f2bf(v);
        }
      }
    }
  }
  __syncthreads();
  // stage 2: out = hc @ Wc2 + bc2
  {
    f32x4 a2[2][3] = {};
#pragma unroll
    for (int ks = 0; ks < 4; ++ks) {
      const int kk = ks * 32 + khi * 8;
      bf16x8 af[2], bq[3];
#pragma unroll
      for (int i = 0; i < 2; i++) {
        int rT = w * 32 + i * 16 + r15;
        af[i] = *(const bf16x8*)&hc[rT * 136 + kk];
      }
#pragma unroll
      for (int j = 0; j < 3; j++) {
        int col = j * 16 + r15;
        bq[j] = *(const bf16x8*)(WtC2 + col * HID + kk);
      }
#pragma unroll
      for (int i = 0; i < 2; i++)
#pragma unroll
        for (int j = 0; j < 3; j++) a2[i][j] = mfma(af[i], bq[j], a2[i][j]);
    }
#pragma unroll
    for (int j = 0; j < 3; j++) {
      const int col = j * 16 + r15;
      const float b = (col < OUTD) ? bc2[col] : 0.f;
#pragma unroll
      for (int i = 0; i < 2; i++) {
        const int rT = w * 32 + i * 16 + khi * 4;
#pragma unroll
        for (int e = 0; e < 4; e++) {
          const int gr = blockIdx.x * 128 + rT + e;
          if (gr < NN && col < OUTD) out[gr * OUTD + col] = a2[i][j][e] + b;
        }
      }
    }
  }
}

// ---------- launch ----------
extern "C" void kernel_launch(void* const* d_in, const int* in_sizes, int n_in,
                              void* d_out, int out_size, void* d_ws, size_t ws_size,
                              hipStream_t stream) {
  (void)in_sizes; (void)n_in; (void)out_size; (void)ws_size;
  const float* x   = (const float*)d_in[0];
  const int*   ei  = (const int*)d_in[1];
  const float* Win = (const float*)d_in[2];
  const float* bin = (const float*)d_in[3];
  const float* Wl  = (const float*)d_in[4];
  const float* Wr  = (const float*)d_in[5];
  const float* bl  = (const float*)d_in[6];
  const float* Wc1 = (const float*)d_in[7];
  const float* bc1 = (const float*)d_in[8];
  const float* Wc2 = (const float*)d_in[9];
  const float* bc2 = (const float*)d_in[10];
  float* out = (float*)d_out;

  char* ws = (char*)d_ws;
  size_t off = 0;
  auto take = [&](size_t bytes) -> char* {
    char* p = ws + off; off = (off + bytes + 255) & ~(size_t)255; return p;
  };
  int* deg        = (int*)take((size_t)NN * 4);
  int* offs       = (int*)take((size_t)(NN + 1) * 4);
  int* pos        = (int*)take((size_t)NE * 4);
  int* bsum       = (int*)take(256 * 4);
  float* dinv     = (float*)take((size_t)NN * 4);
  int* csr        = (int*)take((size_t)NE * 4);
  unsigned short* wt  = (unsigned short*)take((size_t)(8 * 16384 + 48 * 128) * 2);
  unsigned short* h0  = (unsigned short*)take((size_t)NN * HID * 2);
  unsigned short* h1  = (unsigned short*)take((size_t)NN * HID * 2);
  unsigned short* h2  = (unsigned short*)take((size_t)NN * HID * 2);
  unsigned short* h3  = (unsigned short*)take((size_t)NN * HID * 2);
  unsigned short* agg = (unsigned short*)take((size_t)NN * HID * 2);
  unsigned short* part = (unsigned short*)take((size_t)NN * HID * 2);

  const int* esrc = ei;
  const int* edst = ei + NE;

  k_prep<<<(8 * 16384 + 48 * 128 + 255) / 256, 256, 0, stream>>>(Win, Wl, Wr, Wc1, Wc2, wt, deg);
  k_deg_lin<<<LIN_BLKS + DEG_BLKS, 256, 0, stream>>>(edst, deg, pos, x, wt, bin, h0);
  k_blocksum<<<NBLK, 256, 0, stream>>>(deg, bsum);
  k_scan3<<<NBLK, 256, 0, stream>>>(deg, bsum, offs, dinv);
  k_fill<<<(NE + 255) / 256, 256, 0, stream>>>(esrc, edst, pos, offs, csr);

  unsigned short* hs[4] = {h0, h1, h2, h3};
  for (int i = 0; i < 3; i++) {
    k_agg_lin<<<LIN_BLKS + AGG_BLKS, 256, 0, stream>>>(hs[i], csr, offs, dinv, agg,
                                                       wt + (1 + i) * 16384, bl + i * HID, part);
    k_layer2<<<LIN_BLKS, 256, 0, stream>>>(part, agg, wt + (4 + i) * 16384, hs[i + 1]);
  }
  k_cls<<<(NN + 127) / 128, 256, 0, stream>>>(h1, h2, h3, wt + 7 * 16384, bc1,
                                              wt + 8 * 16384, bc2, out);
}

// Round 16
// 234.175 us; speedup vs baseline: 1.3955x; 1.3955x over previous
//
#include <hip/hip_runtime.h>

#define NN   50000
#define NE   800000
#define HID  128
#define OUTD 40
#define NBLK 196  // ceil(NN/256)
#define LIN_BLKS ((NN + 127) / 128)   // 391
#define DEG_BLKS ((NE + 255) / 256)   // 3125
#define NREP 8

typedef float f32x4  __attribute__((ext_vector_type(4)));
typedef int   i32x4  __attribute__((ext_vector_type(4)));
typedef short bf16x8 __attribute__((ext_vector_type(8)));

// ---------- helpers ----------
__device__ __forceinline__ f32x4 mfma(bf16x8 a, bf16x8 b, f32x4 c) {
  return __builtin_amdgcn_mfma_f32_16x16x32_bf16(a, b, c, 0, 0, 0);
}
__device__ __forceinline__ unsigned short f2bf(float f) {
  unsigned u = __builtin_bit_cast(unsigned, f);
  u += 0x7fffu + ((u >> 16) & 1u);
  return (unsigned short)(u >> 16);
}
__device__ __forceinline__ unsigned pack2(float lo, float hi) {
  return (unsigned)f2bf(lo) | ((unsigned)f2bf(hi) << 16);
}
__device__ __forceinline__ float bflo(unsigned v){ return __builtin_bit_cast(float, v << 16); }
__device__ __forceinline__ float bfhi(unsigned v){ return __builtin_bit_cast(float, v & 0xffff0000u); }
__device__ __forceinline__ void acc8(float* a, uint4 v) {
  a[0] += bflo(v.x); a[1] += bfhi(v.x);
  a[2] += bflo(v.y); a[3] += bfhi(v.y);
  a[4] += bflo(v.z); a[5] += bfhi(v.z);
  a[6] += bflo(v.w); a[7] += bfhi(v.w);
}

// blocksum over the 8 replicated degree arrays
__global__ void k_blocksum(const int* __restrict__ deg8, int* __restrict__ bsum) {
  __shared__ int s[256];
  int t = threadIdx.x, i = blockIdx.x * 256 + t;
  int d = 0;
  if (i < NN) {
#pragma unroll
    for (int r = 0; r < NREP; r++) d += deg8[r * NN + i];
  }
  s[t] = d;
  __syncthreads();
  for (int o = 128; o > 0; o >>= 1) { if (t < o) s[t] += s[t + o]; __syncthreads(); }
  if (t == 0) bsum[blockIdx.x] = s[0];
}

// fused: per-block exclusive base + local scan; also emits per-replica
// absolute bases abs8[r][n] = offs[n] + sum_{r'<r} deg8[r'][n]
__global__ void k_scan3(const int* __restrict__ deg8, const int* __restrict__ bsum,
                        int* __restrict__ offs, float* __restrict__ dinv,
                        int* __restrict__ abs8) {
  __shared__ int sb[256];
  __shared__ int s[256];
  int t = threadIdx.x, i = blockIdx.x * 256 + t;
  sb[t] = (t < NBLK && t < blockIdx.x) ? bsum[t] : 0;
  int dr[NREP];
  int v = 0;
  if (i < NN) {
#pragma unroll
    for (int r = 0; r < NREP; r++) { dr[r] = deg8[r * NN + i]; v += dr[r]; }
  }
  s[t] = v;
  __syncthreads();
  for (int o = 128; o > 0; o >>= 1) { if (t < o) sb[t] += sb[t + o]; __syncthreads(); }
  for (int o = 1; o < 256; o <<= 1) {
    int x = (t >= o) ? s[t - o] : 0;
    __syncthreads(); s[t] += x; __syncthreads();
  }
  int off = sb[0] + s[t] - v;  // exclusive within-array offset
  if (i < NN) {
    offs[i] = off;
    dinv[i] = 1.0f / (float)(v > 0 ? v : 1);
    int running = off;
#pragma unroll
    for (int r = 0; r < NREP; r++) { abs8[r * NN + i] = running; running += dr[r]; }
  }
  if (i == 0) offs[NN] = NE;
}

// no atomics: replica base + within-replica rank
__global__ void k_fill(const int* __restrict__ src, const int* __restrict__ dst,
                       const int* __restrict__ pos, const int* __restrict__ abs8,
                       int* __restrict__ csr) {
  int i = blockIdx.x * blockDim.x + threadIdx.x;
  if (i < NE) {
    int r = i & (NREP - 1);
    csr[abs8[r * NN + dst[i]] + pos[i]] = src[i];
  }
}

// ---------- weight prep: transpose + bf16 cast into ws; also zeros deg8 -------
// wt layout: m=0 WtIn, m=1..3 WtL[i], m=4..6 WtR[i], m=7 WtC1, then WtC2 [48][128]
__global__ void k_prep(const float* __restrict__ Win, const float* __restrict__ Wl,
                       const float* __restrict__ Wr, const float* __restrict__ Wc1,
                       const float* __restrict__ Wc2, unsigned short* __restrict__ wt,
                       int* __restrict__ deg8) {
  int idx = blockIdx.x * 256 + threadIdx.x;
  const int NT = ((8 * 16384 + 48 * 128 + 255) / 256) * 256;
  for (int j = idx; j < NREP * NN; j += NT) deg8[j] = 0;  // folded memset (8 copies)
  const int NMAIN = 8 * 16384;
  if (idx >= NMAIN + 48 * 128) return;
  float v;
  if (idx < NMAIN) {
    int m = idx >> 14, rem = idx & 16383;
    int n = rem >> 7, k = rem & 127;
    const float* s;
    if (m == 0) s = Win;
    else if (m <= 3) s = Wl + (m - 1) * 16384;
    else if (m <= 6) s = Wr + (m - 4) * 16384;
    else s = Wc1;
    v = s[k * 128 + n];
  } else {
    int rem = idx - NMAIN;
    int n = rem >> 7, k = rem & 127;
    v = (n < OUTD) ? Wc2[k * OUTD + n] : 0.f;
  }
  wt[idx] = f2bf(v);
}

// ---------- lin_in body (r10 k_lin_in, as device function) ----------
__device__ __forceinline__ void lin_in_body(int bid, const float* __restrict__ x,
                                            const unsigned short* __restrict__ Wt,
                                            const float* __restrict__ bias,
                                            unsigned short* __restrict__ hout) {
  const int lane = threadIdx.x & 63, w = threadIdx.x >> 6;
  const int wr = w >> 1, wc = w & 1;
  const int r15 = lane & 15, khi = lane >> 4;
  const int mbase = bid * 128 + wr * 64, nbase = wc * 64;
  f32x4 acc[4][4] = {};
#pragma unroll
  for (int ks = 0; ks < 4; ++ks) {
    const int kk = ks * 32 + khi * 8;
    bf16x8 af[4], bq[4];
#pragma unroll
    for (int i = 0; i < 4; i++) {
      int row = mbase + i * 16 + r15; row = row < NN ? row : NN - 1;
      const f32x4* p = (const f32x4*)(x + row * HID + kk);
      f32x4 lo = p[0], hi = p[1];
      i32x4 t;
      t[0] = pack2(lo[0], lo[1]); t[1] = pack2(lo[2], lo[3]);
      t[2] = pack2(hi[0], hi[1]); t[3] = pack2(hi[2], hi[3]);
      af[i] = __builtin_bit_cast(bf16x8, t);
    }
#pragma unroll
    for (int j = 0; j < 4; j++) {
      int col = nbase + j * 16 + r15;
      bq[j] = *(const bf16x8*)(Wt + col * HID + kk);
    }
#pragma unroll
    for (int i = 0; i < 4; i++)
#pragma unroll
      for (int j = 0; j < 4; j++) acc[i][j] = mfma(af[i], bq[j], acc[i][j]);
  }
  float b4[4];
#pragma unroll
  for (int j = 0; j < 4; j++) b4[j] = bias[nbase + j * 16 + r15];
#pragma unroll
  for (int i = 0; i < 4; i++) {
    const int rb = mbase + i * 16 + khi * 4;
#pragma unroll
    for (int e = 0; e < 4; e++) {
      const int r = rb + e;
      if (r < NN) {
#pragma unroll
        for (int j = 0; j < 4; j++)
          hout[r * HID + nbase + j * 16 + r15] = f2bf(acc[i][j][e] + b4[j]);
      }
    }
  }
}

// ---------- fused: h0 GEMM (blocks 0..390) || deg count+rank (blocks 391..) --
// Atomics go to replica (edge & 7): 8x the active cache lines -> 8x the
// memory-side same-line atomic parallelism.
__global__ __launch_bounds__(256) void k_deg_lin(const int* __restrict__ dst,
                                                 int* __restrict__ deg8,
                                                 int* __restrict__ pos,
                                                 const float* __restrict__ x,
                                                 const unsigned short* __restrict__ Wt,
                                                 const float* __restrict__ bias,
                                                 unsigned short* __restrict__ hout) {
  if (blockIdx.x < LIN_BLKS) {
    lin_in_body(blockIdx.x, x, Wt, bias, hout);
  } else {
    int i = (blockIdx.x - LIN_BLKS) * 256 + threadIdx.x;
    if (i < NE) {
      int r = i & (NREP - 1);
      pos[i] = atomicAdd(&deg8[r * NN + dst[i]], 1);
    }
  }
}

// ---------- aggregation: quarter-wave uint4, 8 rows/iter via 2 banks (r10) ----
__global__ __launch_bounds__(256) void k_agg(const unsigned short* __restrict__ h,
                                             const int* __restrict__ csr,
                                             const int* __restrict__ offs,
                                             const float* __restrict__ dinv,
                                             unsigned short* __restrict__ agg) {
  const int lane = threadIdx.x & 63;
  const int c = lane & 15;   // uint4 index within row (16 x 16B = 256B)
  const int q = lane >> 4;   // quarter 0..3: row within 4-row group
  int gw = (blockIdx.x * 256 + (int)threadIdx.x) >> 6;
  const int nw = (gridDim.x * 256) >> 6;
  const uint4* h4 = (const uint4*)h;  // row stride = 16 uint4
  uint4* ag4 = (uint4*)agg;
  for (int n = gw; n < NN; n += nw) {
    const int s = offs[n], e = offs[n + 1];
    float a[8] = {0, 0, 0, 0, 0, 0, 0, 0};
    float b[8] = {0, 0, 0, 0, 0, 0, 0, 0};
    int k = s;
    int ia = 0, ib = 0;
    bool have = (k + 8 <= e);
    if (have) { ia = csr[k + q]; ib = csr[k + 4 + q]; }
    while (have) {
      uint4 va = h4[ia * 16 + c];
      uint4 vb = h4[ib * 16 + c];
      k += 8;
      have = (k + 8 <= e);
      if (have) { ia = csr[k + q]; ib = csr[k + 4 + q]; }  // prefetch next batch
      acc8(a, va);
      acc8(b, vb);
    }
    for (; k < e; k += 4) {  // tail 1-7 rows, predicated per quarter
      if (k + q < e) {
        uint4 v = h4[csr[k + q] * 16 + c];
        acc8(a, v);
      }
    }
    float f0 = a[0] + b[0], f1 = a[1] + b[1], f2 = a[2] + b[2], f3 = a[3] + b[3];
    float f4 = a[4] + b[4], f5 = a[5] + b[5], f6 = a[6] + b[6], f7 = a[7] + b[7];
    f0 += __shfl_xor(f0, 16); f1 += __shfl_xor(f1, 16);
    f2 += __shfl_xor(f2, 16); f3 += __shfl_xor(f3, 16);
    f4 += __shfl_xor(f4, 16); f5 += __shfl_xor(f5, 16);
    f6 += __shfl_xor(f6, 16); f7 += __shfl_xor(f7, 16);
    f0 += __shfl_xor(f0, 32); f1 += __shfl_xor(f1, 32);
    f2 += __shfl_xor(f2, 32); f3 += __shfl_xor(f3, 32);
    f4 += __shfl_xor(f4, 32); f5 += __shfl_xor(f5, 32);
    f6 += __shfl_xor(f6, 32); f7 += __shfl_xor(f7, 32);
    if (q == 0) {
      float di = dinv[n];
      uint4 o;
      o.x = pack2(f0 * di, f1 * di);
      o.y = pack2(f2 * di, f3 * di);
      o.z = pack2(f4 * di, f5 * di);
      o.w = pack2(f6 * di, f7 * di);
      ag4[n * 16 + c] = o;
    }
  }
}

// ---------- GEMM: h_new = relu(h @ Wl + agg @ Wr + bl) (bf16 in/out) ----------
__global__ __launch_bounds__(256) void k_layer(const unsigned short* __restrict__ hp,
                                               const unsigned short* __restrict__ ag,
                                               const unsigned short* __restrict__ WtL,
                                               const unsigned short* __restrict__ WtR,
                                               const float* __restrict__ bias,
                                               unsigned short* __restrict__ hout) {
  const int lane = threadIdx.x & 63, w = threadIdx.x >> 6;
  const int wr = w >> 1, wc = w & 1;
  const int r15 = lane & 15, khi = lane >> 4;
  const int mbase = blockIdx.x * 128 + wr * 64, nbase = wc * 64;
  f32x4 acc[4][4] = {};
#pragma unroll
  for (int ph = 0; ph < 2; ++ph) {
    const unsigned short* A = ph ? ag : hp;
    const unsigned short* B = ph ? WtR : WtL;
#pragma unroll
    for (int ks = 0; ks < 4; ++ks) {
      const int kk = ks * 32 + khi * 8;
      bf16x8 af[4], bq[4];
#pragma unroll
      for (int i = 0; i < 4; i++) {
        int row = mbase + i * 16 + r15; row = row < NN ? row : NN - 1;
        af[i] = *(const bf16x8*)(A + row * HID + kk);
      }
#pragma unroll
      for (int j = 0; j < 4; j++) {
        int col = nbase + j * 16 + r15;
        bq[j] = *(const bf16x8*)(B + col * HID + kk);
      }
#pragma unroll
      for (int i = 0; i < 4; i++)
#pragma unroll
        for (int j = 0; j < 4; j++) acc[i][j] = mfma(af[i], bq[j], acc[i][j]);
    }
  }
  float b4[4];
#pragma unroll
  for (int j = 0; j < 4; j++) b4[j] = bias[nbase + j * 16 + r15];
#pragma unroll
  for (int i = 0; i < 4; i++) {
    const int rb = mbase + i * 16 + khi * 4;
#pragma unroll
    for (int e = 0; e < 4; e++) {
      const int r = rb + e;
      if (r < NN) {
#pragma unroll
        for (int j = 0; j < 4; j++) {
          float v = acc[i][j][e] + b4[j];
          v = fmaxf(v, 0.f);
          hout[r * HID + nbase + j * 16 + r15] = f2bf(v);
        }
      }
    }
  }
}

// ---------- classifier: out = relu((h1+h2+h3)@Wc1+bc1)@Wc2+bc2 ----------
__global__ __launch_bounds__(256) void k_cls(const unsigned short* __restrict__ h1,
                                             const unsigned short* __restrict__ h2,
                                             const unsigned short* __restrict__ h3,
                                             const unsigned short* __restrict__ WtC1,
                                             const float* __restrict__ bc1,
                                             const unsigned short* __restrict__ WtC2,
                                             const float* __restrict__ bc2,
                                             float* __restrict__ out) {
  __shared__ unsigned short hc[128 * 136];  // padded row stride 136
  const int lane = threadIdx.x & 63, w = threadIdx.x >> 6;
  const int wr = w >> 1, wc = w & 1;
  const int r15 = lane & 15, khi = lane >> 4;
  const int mbase = blockIdx.x * 128 + wr * 64, nbase = wc * 64;
  // stage 1: hc = relu((h1+h2+h3) @ Wc1 + bc1)
  {
    f32x4 acc[4][4] = {};
#pragma unroll
    for (int ks = 0; ks < 4; ++ks) {
      const int kk = ks * 32 + khi * 8;
      bf16x8 af[4], bq[4];
#pragma unroll
      for (int i = 0; i < 4; i++) {
        int row = mbase + i * 16 + r15; row = row < NN ? row : NN - 1;
        i32x4 u = *(const i32x4*)(h1 + row * HID + kk);
        i32x4 v = *(const i32x4*)(h2 + row * HID + kk);
        i32x4 q = *(const i32x4*)(h3 + row * HID + kk);
        i32x4 t;
#pragma unroll
        for (int cc = 0; cc < 4; cc++) {
          unsigned uu = u[cc], vv = v[cc], qq = q[cc];
          t[cc] = pack2(bflo(uu) + bflo(vv) + bflo(qq), bfhi(uu) + bfhi(vv) + bfhi(qq));
        }
        af[i] = __builtin_bit_cast(bf16x8, t);
      }
#pragma unroll
      for (int j = 0; j < 4; j++) {
        int col = nbase + j * 16 + r15;
        bq[j] = *(const bf16x8*)(WtC1 + col * HID + kk);
      }
#pragma unroll
      for (int i = 0; i < 4; i++)
#pragma unroll
        for (int j = 0; j < 4; j++) acc[i][j] = mfma(af[i], bq[j], acc[i][j]);
    }
    float b4[4];
#pragma unroll
    for (int j = 0; j < 4; j++) b4[j] = bc1[nbase + j * 16 + r15];
#pragma unroll
    for (int i = 0; i < 4; i++) {
      const int rT = wr * 64 + i * 16 + khi * 4;
#pragma unroll
      for (int e = 0; e < 4; e++) {
#pragma unroll
        for (int j = 0; j < 4; j++) {
          float v = fmaxf(acc[i][j][e] + b4[j], 0.f);
          hc[(rT + e) * 136 + nbase + j * 16 + r15] = f2bf(v);
        }
      }
    }
  }
  __syncthreads();
  // stage 2: out = hc @ Wc2 + bc2
  {
    f32x4 a2[2][3] = {};
#pragma unroll
    for (int ks = 0; ks < 4; ++ks) {
      const int kk = ks * 32 + khi * 8;
      bf16x8 af[2], bq[3];
#pragma unroll
      for (int i = 0; i < 2; i++) {
        int rT = w * 32 + i * 16 + r15;
        af[i] = *(const bf16x8*)&hc[rT * 136 + kk];
      }
#pragma unroll
      for (int j = 0; j < 3; j++) {
        int col = j * 16 + r15;
        bq[j] = *(const bf16x8*)(WtC2 + col * HID + kk);
      }
#pragma unroll
      for (int i = 0; i < 2; i++)
#pragma unroll
        for (int j = 0; j < 3; j++) a2[i][j] = mfma(af[i], bq[j], a2[i][j]);
    }
#pragma unroll
    for (int j = 0; j < 3; j++) {
      const int col = j * 16 + r15;
      const float b = (col < OUTD) ? bc2[col] : 0.f;
#pragma unroll
      for (int i = 0; i < 2; i++) {
        const int rT = w * 32 + i * 16 + khi * 4;
#pragma unroll
        for (int e = 0; e < 4; e++) {
          const int gr = blockIdx.x * 128 + rT + e;
          if (gr < NN && col < OUTD) out[gr * OUTD + col] = a2[i][j][e] + b;
        }
      }
    }
  }
}

// ---------- launch ----------
extern "C" void kernel_launch(void* const* d_in, const int* in_sizes, int n_in,
                              void* d_out, int out_size, void* d_ws, size_t ws_size,
                              hipStream_t stream) {
  (void)in_sizes; (void)n_in; (void)out_size; (void)ws_size;
  const float* x   = (const float*)d_in[0];
  const int*   ei  = (const int*)d_in[1];
  const float* Win = (const float*)d_in[2];
  const float* bin = (const float*)d_in[3];
  const float* Wl  = (const float*)d_in[4];
  const float* Wr  = (const float*)d_in[5];
  const float* bl  = (const float*)d_in[6];
  const float* Wc1 = (const float*)d_in[7];
  const float* bc1 = (const float*)d_in[8];
  const float* Wc2 = (const float*)d_in[9];
  const float* bc2 = (const float*)d_in[10];
  float* out = (float*)d_out;

  char* ws = (char*)d_ws;
  size_t off = 0;
  auto take = [&](size_t bytes) -> char* {
    char* p = ws + off; off = (off + bytes + 255) & ~(size_t)255; return p;
  };
  int* deg8       = (int*)take((size_t)NREP * NN * 4);
  int* abs8       = (int*)take((size_t)NREP * NN * 4);
  int* offs       = (int*)take((size_t)(NN + 1) * 4);
  int* pos        = (int*)take((size_t)NE * 4);
  int* bsum       = (int*)take(256 * 4);
  float* dinv     = (float*)take((size_t)NN * 4);
  int* csr        = (int*)take((size_t)NE * 4);
  unsigned short* wt  = (unsigned short*)take((size_t)(8 * 16384 + 48 * 128) * 2);
  unsigned short* h0  = (unsigned short*)take((size_t)NN * HID * 2);
  unsigned short* h1  = (unsigned short*)take((size_t)NN * HID * 2);
  unsigned short* h2  = (unsigned short*)take((size_t)NN * HID * 2);
  unsigned short* h3  = (unsigned short*)take((size_t)NN * HID * 2);
  unsigned short* agg = (unsigned short*)take((size_t)NN * HID * 2);

  const int* esrc = ei;
  const int* edst = ei + NE;

  k_prep<<<(8 * 16384 + 48 * 128 + 255) / 256, 256, 0, stream>>>(Win, Wl, Wr, Wc1, Wc2, wt, deg8);
  k_deg_lin<<<LIN_BLKS + DEG_BLKS, 256, 0, stream>>>(edst, deg8, pos, x, wt, bin, h0);
  k_blocksum<<<NBLK, 256, 0, stream>>>(deg8, bsum);
  k_scan3<<<NBLK, 256, 0, stream>>>(deg8, bsum, offs, dinv, abs8);
  k_fill<<<(NE + 255) / 256, 256, 0, stream>>>(esrc, edst, pos, abs8, csr);

  unsigned short* hs[4] = {h0, h1, h2, h3};
  for (int i = 0; i < 3; i++) {
    k_agg<<<2048, 256, 0, stream>>>(hs[i], csr, offs, dinv, agg);
    k_layer<<<(NN + 127) / 128, 256, 0, stream>>>(hs[i], agg, wt + (1 + i) * 16384,
                                                  wt + (4 + i) * 16384, bl + i * HID, hs[i + 1]);
  }
  k_cls<<<(NN + 127) / 128, 256, 0, stream>>>(h1, h2, h3, wt + 7 * 16384, bc1,
                                              wt + 8 * 16384, bc2, out);
}